// Round 5
// baseline (285.313 us; speedup 1.0000x reference)
//
#include <hip/hip_runtime.h>

typedef __attribute__((ext_vector_type(8))) short short8;
typedef __attribute__((ext_vector_type(4))) float f32x4;

// B=4, C=256, pooled N=4096, kc=vc=128, oc=256
static constexpr size_t OFF_SIGMA = 0;
static constexpr size_t OFF_ML    = 256;                                 // float[8sp][16384] row-sums
static constexpr size_t OFF_QKT   = OFF_ML + 1048576;                    // bf16 [4][4096][128] (swizzled cols)
static constexpr size_t OFF_V     = OFF_QKT + (size_t)4*4096*128*2;      // bf16 [4][128][4096] plain
static constexpr size_t OFF_WWB   = OFF_V + (size_t)4*4096*128*2;        // bf16 [256][128]
static constexpr size_t OFF_XF    = OFF_WWB + 65536;                     // f32 [4*256][4096]
static constexpr size_t OFF_PC    = OFF_XF;                              // bf16 [nsp][16384][128] (reuses xf)
static constexpr size_t NEED8     = OFF_PC + (size_t)8*16384*128*2;      // ~43 MB

__device__ inline unsigned short f2bf(float f) {
  unsigned int u = __float_as_uint(f);
  unsigned int r = u + 0x7fffu + ((u >> 16) & 1u);
  return (unsigned short)(r >> 16);
}
__device__ inline float bf2f(unsigned short s) {
  return __uint_as_float(((unsigned int)s) << 16);
}

// ---------------- K1: maxpool3d(2): x[4,256,32,32,32] -> xf[4,256,4096] ----
__launch_bounds__(256)
__global__ void k_maxpool(const float* __restrict__ x, float* __restrict__ xf) {
  int idx = blockIdx.x * 256 + threadIdx.x;      // 2 outputs per thread
  int n2 = idx & 2047;
  int bc = idx >> 11;
  int d2p = n2 & 7, d1 = (n2 >> 3) & 15, d0 = n2 >> 7;
  const float* p = x + (size_t)bc * 32768 + (size_t)d0 * 2048 + d1 * 64 + d2p * 4;
  float4 a = *(const float4*)(p);
  float4 b = *(const float4*)(p + 32);
  float4 c = *(const float4*)(p + 1024);
  float4 e = *(const float4*)(p + 1056);
  float o0 = fmaxf(fmaxf(fmaxf(a.x, a.y), fmaxf(b.x, b.y)),
                   fmaxf(fmaxf(c.x, c.y), fmaxf(e.x, e.y)));
  float o1 = fmaxf(fmaxf(fmaxf(a.z, a.w), fmaxf(b.z, b.w)),
                   fmaxf(fmaxf(c.z, c.w), fmaxf(e.z, e.w)));
  *(float2*)(xf + (size_t)bc * 4096 + n2 * 2) = make_float2(o0, o1);
}

// ---------------- K2: spectral-norm sigma ----------------------------------
__global__ void k_sigma(const float* __restrict__ Wk, const float* __restrict__ u,
                        float* __restrict__ sig) {
  __shared__ float vsh[256];
  __shared__ float red[256];
  __shared__ float ush[128];
  int t = threadIdx.x;
  if (t < 128) ush[t] = u[t];
  __syncthreads();
  float acc = 0.f;
  for (int k = 0; k < 128; k++) acc += Wk[(size_t)k * 256 + t] * ush[k];
  vsh[t] = acc;
  red[t] = acc * acc;
  __syncthreads();
  for (int s = 128; s > 0; s >>= 1) { if (t < s) red[t] += red[t + s]; __syncthreads(); }
  float nrm = sqrtf(red[0]) + 1e-12f;
  float vn = vsh[t] / nrm;
  __syncthreads();
  vsh[t] = vn;
  __syncthreads();
  float acc2 = 0.f;
  if (t < 128) {
    for (int c = 0; c < 256; c++) acc2 += Wk[(size_t)t * 256 + c] * vsh[c];
  }
  red[t] = (t < 128) ? acc2 * acc2 : 0.f;
  __syncthreads();
  for (int s = 128; s > 0; s >>= 1) { if (t < s) red[t] += red[t + s]; __syncthreads(); }
  if (t == 0) {
    float s2v = red[0];
    sig[0] = s2v / (sqrtf(s2v) + 1e-12f);
  }
}

// ---------------- K2b: Ww f32 -> bf16 --------------------------------------
__launch_bounds__(256)
__global__ void k_prep(const float* __restrict__ Ww, unsigned short* __restrict__ wwb) {
  int i = (blockIdx.x * 256 + threadIdx.x) * 4;       // 32768 total
  float4 w = *(const float4*)(Ww + i);
  unsigned int lo = (unsigned int)f2bf(w.x) | ((unsigned int)f2bf(w.y) << 16);
  unsigned int hi = (unsigned int)f2bf(w.z) | ((unsigned int)f2bf(w.w) << 16);
  *(uint2*)(wwb + i) = make_uint2(lo, hi);
}

// ---------------- K3: fused projections ------------------------------------
// K store swizzled: qkT[b][n][ ((d>>3)^(n&7))*8 + d&7 ];  V store plain [b][d][n]
__launch_bounds__(256)
__global__ void k_qkv(const float* __restrict__ xf,
                      const float* __restrict__ Wk, const float* __restrict__ bk,
                      const float* __restrict__ Wv, const float* __restrict__ bv,
                      const float* __restrict__ sig,
                      unsigned short* __restrict__ qkT, unsigned short* __restrict__ vws) {
  __shared__ float Wl[16][68];
  __shared__ float Xl[16][68];
  int bid = blockIdx.x;
  int ntile = bid & 63, rt = (bid >> 6) & 3, b = bid >> 8;
  int r0 = rt * 64, n0 = ntile * 64;
  int t = threadIdx.x, tx = t & 15, ty = t >> 4;
  float acc[4][4] = {};
  for (int c0 = 0; c0 < 256; c0 += 16) {
#pragma unroll
    for (int i = 0; i < 4; i++) {
      int li = t + i * 256;
      int rr = li >> 4, cc = li & 15;
      int R = r0 + rr;
      Wl[cc][rr] = (R < 128) ? Wk[(size_t)R * 256 + c0 + cc]
                             : Wv[(size_t)(R - 128) * 256 + c0 + cc];
    }
#pragma unroll
    for (int i = 0; i < 4; i++) {
      int li = t + i * 256;
      int nn = li & 63, cc = li >> 6;
      Xl[cc][nn] = xf[((size_t)(b * 256 + c0 + cc)) * 4096 + n0 + nn];
    }
    __syncthreads();
#pragma unroll
    for (int cc = 0; cc < 16; cc++) {
      float4 a4 = *(const float4*)&Wl[cc][ty * 4];
      float4 b4 = *(const float4*)&Xl[cc][tx * 4];
      float av[4] = {a4.x, a4.y, a4.z, a4.w};
      float bvv[4] = {b4.x, b4.y, b4.z, b4.w};
#pragma unroll
      for (int i = 0; i < 4; i++)
#pragma unroll
        for (int j = 0; j < 4; j++) acc[i][j] += av[i] * bvv[j];
    }
    __syncthreads();
  }
  float inv_s = 1.0f / sig[0];
#pragma unroll
  for (int i = 0; i < 4; i++) {
    int R = r0 + ty * 4 + i;
#pragma unroll
    for (int j = 0; j < 4; j++) {
      int n = n0 + tx * 4 + j;
      if (R < 128) {
        float val = acc[i][j] * inv_s + bk[R];
        int ds = ((((R >> 3) ^ (n & 7)) & 15) << 3) | (R & 7);
        qkT[((size_t)b * 4096 + n) * 128 + ds] = f2bf(val);
      } else {
        int d = R - 128;
        float val = acc[i][j] + bv[d];
        vws[((size_t)(b * 128 + d)) * 4096 + n] = f2bf(val);
      }
    }
  }
}

// ---------------- K4: flash attention, no-max softmax, V from L2 -----------
// grid 128*nsp. 4 waves, 32 q-rows/wave. K staged in LDS (reg dbuf);
// V read direct as B-frags (L2-resident); P per-wave LDS; l deferred-reduced.
__launch_bounds__(256, 4)
__global__ void k_attn(const unsigned short* __restrict__ qkT,
                       const unsigned short* __restrict__ vws,
                       unsigned short* __restrict__ pc, float* __restrict__ lsum,
                       int nsp, int spbits) {
  __shared__ __align__(16) char smem[16384 + 4 * 4608];  // K 16K | P 4x4.5K
  const float C1 = 0.12751744f;        // (1/sqrt(128)) * log2(e)
  int nwg = gridDim.x;
  int p = blockIdx.x;
  int bid = (p & 7) * (nwg >> 3) + (p >> 3);             // XCD swizzle
  int sp = bid & (nsp - 1);
  int qt = (bid >> spbits) & 31;
  int b = bid >> (spbits + 5);
  int iters = 64 >> spbits;
  int kv0 = sp << (12 - spbits);
  int t = threadIdx.x, wid = t >> 6, lane = t & 63, g = lane >> 4, lr = lane & 15;
  int qrb = qt * 128 + wid * 32;
  const unsigned short* qk_b = qkT + (size_t)b * 524288;
  const char* kgb = (const char*)qk_b;
  const unsigned short* v_b = vws + (size_t)b * 524288;
  char* KL = smem;
  unsigned short* PL = (unsigned short*)(smem + 16384 + wid * 4608);  // [32][72]

  // Q fragments (unswizzle stored layout)
  short8 qf[2][4];
#pragma unroll
  for (int rt = 0; rt < 2; rt++)
#pragma unroll
    for (int kk = 0; kk < 4; kk++) {
      int row = qrb + rt * 16 + lr;
      qf[rt][kk] = *(const short8*)(qk_b + (size_t)row * 128 +
                                    ((((kk * 4 + g) ^ (lr & 7)) & 15) << 3));
    }

  f32x4 cacc[2][8];
#pragma unroll
  for (int rt = 0; rt < 2; rt++)
#pragma unroll
    for (int vt = 0; vt < 8; vt++) cacc[rt][vt] = (f32x4){0.f, 0.f, 0.f, 0.f};
  float l0[4] = {0.f, 0.f, 0.f, 0.f}, l1[4] = {0.f, 0.f, 0.f, 0.f};

  short8 kst[4];
  {
    const char* kg = kgb + (size_t)kv0 * 256;
#pragma unroll
    for (int i = 0; i < 4; i++) kst[i] = *(const short8*)(kg + i * 4096 + t * 16);
  }

#pragma unroll 1
  for (int it = 0; it < iters; ++it) {
    int mbase = kv0 + it * 64;
    __syncthreads();
#pragma unroll
    for (int i = 0; i < 4; i++) *(short8*)(KL + i * 4096 + t * 16) = kst[i];
    if (it < iters - 1) {
      const char* kg = kgb + (size_t)(mbase + 64) * 256;
#pragma unroll
      for (int i = 0; i < 4; i++) kst[i] = *(const short8*)(kg + i * 4096 + t * 16);
    }
    __syncthreads();

    // ---- QK^T ----
    f32x4 s0[4], s1[4];
    __builtin_amdgcn_s_setprio(1);
#pragma unroll
    for (int ct = 0; ct < 4; ct++) {
      short8 kf[4];
#pragma unroll
      for (int kk = 0; kk < 4; kk++)
        kf[kk] = *(const short8*)(KL + (ct * 16 + lr) * 256 +
                                  ((((kk * 4 + g) ^ (lr & 7)) & 15) << 4));
      f32x4 a0 = {0.f, 0.f, 0.f, 0.f}, a1 = a0;
#pragma unroll
      for (int kk = 0; kk < 4; kk++) {
        a0 = __builtin_amdgcn_mfma_f32_16x16x32_bf16(qf[0][kk], kf[kk], a0, 0, 0, 0);
        a1 = __builtin_amdgcn_mfma_f32_16x16x32_bf16(qf[1][kk], kf[kk], a1, 0, 0, 0);
      }
      s0[ct] = a0;
      s1[ct] = a1;
    }
    __builtin_amdgcn_s_setprio(0);

    // ---- no-max softmax: P = exp2(C1*s); per-lane partial row-sums ----
#pragma unroll
    for (int ct = 0; ct < 4; ct++)
#pragma unroll
      for (int r = 0; r < 4; r++) {
        float p0 = __builtin_amdgcn_exp2f(s0[ct][r] * C1);
        float p1 = __builtin_amdgcn_exp2f(s1[ct][r] * C1);
        l0[r] += p0;
        l1[r] += p1;
        PL[(g * 4 + r) * 72 + ct * 16 + lr] =
            (unsigned short)((__float_as_uint(p0) + 0x8000u) >> 16);
        PL[(16 + g * 4 + r) * 72 + ct * 16 + lr] =
            (unsigned short)((__float_as_uint(p1) + 0x8000u) >> 16);
      }

    // ---- PV: P from LDS (A), V direct from L2 (B) ----
    __builtin_amdgcn_s_setprio(1);
#pragma unroll
    for (int ks = 0; ks < 2; ks++) {
      short8 pa0 = *(const short8*)(PL + lr * 72 + ks * 32 + g * 8);
      short8 pa1 = *(const short8*)(PL + (16 + lr) * 72 + ks * 32 + g * 8);
#pragma unroll
      for (int vt = 0; vt < 8; vt++) {
        short8 vb = *(const short8*)(v_b + (size_t)(vt * 16 + lr) * 4096 +
                                     mbase + ks * 32 + g * 8);
        cacc[0][vt] = __builtin_amdgcn_mfma_f32_16x16x32_bf16(pa0, vb, cacc[0][vt], 0, 0, 0);
        cacc[1][vt] = __builtin_amdgcn_mfma_f32_16x16x32_bf16(pa1, vb, cacc[1][vt], 0, 0, 0);
      }
    }
    __builtin_amdgcn_s_setprio(0);
  }

  // ---- deferred l reduce (over 16-lane group) ----
#pragma unroll
  for (int r = 0; r < 4; r++) {
    float v = l0[r];
    v += __shfl_xor(v, 1); v += __shfl_xor(v, 2);
    v += __shfl_xor(v, 4); v += __shfl_xor(v, 8);
    l0[r] = v;
    float w = l1[r];
    w += __shfl_xor(w, 1); w += __shfl_xor(w, 2);
    w += __shfl_xor(w, 4); w += __shfl_xor(w, 8);
    l1[r] = w;
  }

  // ---- epilogue: bf16 partials + l ----
#pragma unroll
  for (int rt = 0; rt < 2; rt++)
#pragma unroll
    for (int vt = 0; vt < 8; vt++)
#pragma unroll
      for (int r = 0; r < 4; r++) {
        int n = qrb + rt * 16 + g * 4 + r;
        size_t gn = (size_t)b * 4096 + n;
        float v = rt ? cacc[1][vt][r] : cacc[0][vt][r];
        pc[((size_t)sp * 16384 + gn) * 128 + vt * 16 + lr] = f2bf(v);
      }
  if (lr == 0) {
#pragma unroll
    for (int rt = 0; rt < 2; rt++)
#pragma unroll
      for (int r = 0; r < 4; r++) {
        int n = qrb + rt * 16 + g * 4 + r;
        size_t gn = (size_t)b * 4096 + n;
        lsum[sp * 16384 + gn] = rt ? l1[r] : l0[r];
      }
  }
}

// ---------------- K5: fused merge + output projection (MFMA) ---------------
__launch_bounds__(256)
__global__ void k_mergeout(const unsigned short* __restrict__ pc,
                           const float* __restrict__ lsum,
                           const unsigned short* __restrict__ wwb,
                           const float* __restrict__ bw,
                           float* __restrict__ out, int nsp) {
  __shared__ float inv_l[64];
  __shared__ __align__(16) unsigned short Bl[64 * 128];
  int bid = blockIdx.x;
  int nt = bid & 63, b = bid >> 6;
  int n0 = nt * 64;
  size_t gnb = (size_t)b * 4096 + n0;
  int t = threadIdx.x;

  if (t < 64) {
    float L = 0.f;
    for (int sp = 0; sp < nsp; sp++) L += lsum[sp * 16384 + gnb + t];
    inv_l[t] = 1.f / L;
  }
  __syncthreads();

  {  // merge 32 values per thread: n = t&63, v = (t>>6)*32 ..
    int n = t & 63, vs = t >> 6;
    float o[32] = {};
    for (int sp = 0; sp < nsp; sp++) {
      const unsigned short* src = pc + ((size_t)sp * 16384 + gnb + n) * 128 + vs * 32;
#pragma unroll
      for (int c = 0; c < 4; c++) {
        short8 pv = *(const short8*)(src + c * 8);
#pragma unroll
        for (int j = 0; j < 8; j++) o[c * 8 + j] += bf2f((unsigned short)pv[j]);
      }
    }
    float inv = inv_l[n];
    unsigned int* B32 = (unsigned int*)Bl;
#pragma unroll
    for (int jj = 0; jj < 16; jj++) {
      int v = vs * 32 + jj * 2;
      int kg = v >> 3;
      int kgp = (kg & 8) | ((kg ^ n) & 7);
      unsigned int pk = (unsigned int)f2bf(o[jj * 2] * inv) |
                        ((unsigned int)f2bf(o[jj * 2 + 1] * inv) << 16);
      B32[n * 64 + kgp * 4 + ((v & 7) >> 1)] = pk;
    }
  }
  __syncthreads();

  int wid = t >> 6, lane = t & 63, g = lane >> 4, lr = lane & 15;
  int o0 = wid * 64;
  short8 af[4][4];
#pragma unroll
  for (int ot = 0; ot < 4; ot++) {
    int o = o0 + ot * 16 + lr;
#pragma unroll
    for (int ks = 0; ks < 4; ks++)
      af[ot][ks] = *(const short8*)(wwb + (size_t)o * 128 + ks * 32 + g * 8);
  }
  f32x4 acc[4][4];
#pragma unroll
  for (int i = 0; i < 4; i++)
#pragma unroll
    for (int j = 0; j < 4; j++) acc[i][j] = (f32x4){0.f, 0.f, 0.f, 0.f};
#pragma unroll
  for (int nt2 = 0; nt2 < 4; nt2++) {
    short8 bfr[4];
#pragma unroll
    for (int ks = 0; ks < 4; ks++) {
      int kg = ks * 4 + g;
      int kgp = (kg & 8) | ((kg ^ lr) & 7);
      bfr[ks] = *(const short8*)(Bl + (nt2 * 16 + lr) * 128 + kgp * 8);
    }
#pragma unroll
    for (int ot = 0; ot < 4; ot++)
#pragma unroll
      for (int ks = 0; ks < 4; ks++)
        acc[ot][nt2] = __builtin_amdgcn_mfma_f32_16x16x32_bf16(af[ot][ks], bfr[ks],
                                                               acc[ot][nt2], 0, 0, 0);
  }
#pragma unroll
  for (int ot = 0; ot < 4; ot++)
#pragma unroll
    for (int r = 0; r < 4; r++) {
      int o = o0 + ot * 16 + g * 4 + r;
      float bias = bw[o];
#pragma unroll
      for (int nt2 = 0; nt2 < 4; nt2++)
        out[((size_t)(b * 256 + o)) * 4096 + n0 + nt2 * 16 + lr] = acc[ot][nt2][r] + bias;
    }
}

extern "C" void kernel_launch(void* const* d_in, const int* in_sizes, int n_in,
                              void* d_out, int out_size, void* d_ws, size_t ws_size,
                              hipStream_t stream) {
  const float* x  = (const float*)d_in[0];
  const float* Wk = (const float*)d_in[1];
  const float* bk = (const float*)d_in[2];
  const float* Wv = (const float*)d_in[3];
  const float* bv = (const float*)d_in[4];
  const float* Ww = (const float*)d_in[5];
  const float* bw = (const float*)d_in[6];
  const float* u  = (const float*)d_in[7];

  char* ws = (char*)d_ws;
  float* sig            = (float*)(ws + OFF_SIGMA);
  float* lsum           = (float*)(ws + OFF_ML);
  unsigned short* qkT   = (unsigned short*)(ws + OFF_QKT);
  unsigned short* vbuf  = (unsigned short*)(ws + OFF_V);
  unsigned short* wwb   = (unsigned short*)(ws + OFF_WWB);
  float* xf             = (float*)(ws + OFF_XF);
  unsigned short* pc    = (unsigned short*)(ws + OFF_PC);
  float* out            = (float*)d_out;

  int nsp    = (ws_size >= NEED8) ? 8 : 4;
  int spbits = (nsp == 8) ? 3 : 2;

  k_maxpool<<<8192, 256, 0, stream>>>(x, xf);
  k_sigma<<<1, 256, 0, stream>>>(Wk, u, sig);
  k_prep<<<32, 256, 0, stream>>>(Ww, wwb);
  k_qkv<<<1024, 256, 0, stream>>>(xf, Wk, bk, Wv, bv, sig, qkT, vbuf);
  k_attn<<<128 * nsp, 256, 0, stream>>>(qkT, vbuf, pc, lsum, nsp, spbits);
  k_mergeout<<<256, 256, 0, stream>>>(pc, lsum, wwb, bw, out, nsp);
}

// Round 6
// 251.089 us; speedup vs baseline: 1.1363x; 1.1363x over previous
//
#include <hip/hip_runtime.h>

typedef __attribute__((ext_vector_type(8))) short short8;
typedef __attribute__((ext_vector_type(4))) float f32x4;

// B=4, C=256, pooled N=4096, kc=vc=128, oc=256
static constexpr size_t OFF_SIGMA = 0;
static constexpr size_t OFF_ML    = 256;                        // float[8][16384] row-sums
static constexpr size_t OFF_QKT   = 1048576;                    // bf16 [4][4096][128] (col-swizzled)
static constexpr size_t OFF_V     = OFF_QKT + 4194304;          // bf16 [4][128][4096] (64-tile swizzled)
static constexpr size_t OFF_WCAT  = OFF_V + 4194304;            // bf16 Ww[256][128] | Wk[128][256] | Wv[128][256]
static constexpr size_t OFF_XFB   = OFF_WCAT + 196608;          // bf16 [4*256][4096]
static constexpr size_t OFF_PC    = OFF_XFB;                    // bf16 [8][16384][128] (aliases xfb; xfb dead by attn)

__device__ inline unsigned short f2bf(float f) {
  unsigned int u = __float_as_uint(f);
  unsigned int r = u + 0x7fffu + ((u >> 16) & 1u);
  return (unsigned short)(r >> 16);
}
__device__ inline float bf2f(unsigned short s) {
  return __uint_as_float(((unsigned int)s) << 16);
}

// ---------------- K1: maxpool3d(2) -> xfb bf16 [4,256,4096] ----------------
__launch_bounds__(256)
__global__ void k_maxpool(const float* __restrict__ x, unsigned short* __restrict__ xfb) {
  int idx = blockIdx.x * 256 + threadIdx.x;      // 2 outputs per thread
  int n2 = idx & 2047;
  int bc = idx >> 11;
  int d2p = n2 & 7, d1 = (n2 >> 3) & 15, d0 = n2 >> 7;
  const float* p = x + (size_t)bc * 32768 + (size_t)d0 * 2048 + d1 * 64 + d2p * 4;
  float4 a = *(const float4*)(p);
  float4 b = *(const float4*)(p + 32);
  float4 c = *(const float4*)(p + 1024);
  float4 e = *(const float4*)(p + 1056);
  float o0 = fmaxf(fmaxf(fmaxf(a.x, a.y), fmaxf(b.x, b.y)),
                   fmaxf(fmaxf(c.x, c.y), fmaxf(e.x, e.y)));
  float o1 = fmaxf(fmaxf(fmaxf(a.z, a.w), fmaxf(b.z, b.w)),
                   fmaxf(fmaxf(c.z, c.w), fmaxf(e.z, e.w)));
  unsigned int pk = (unsigned int)f2bf(o0) | ((unsigned int)f2bf(o1) << 16);
  *(unsigned int*)(xfb + (size_t)bc * 4096 + n2 * 2) = pk;
}

// ---------------- K2: spectral-norm sigma ----------------------------------
__global__ void k_sigma(const float* __restrict__ Wk, const float* __restrict__ u,
                        float* __restrict__ sig) {
  __shared__ float vsh[256];
  __shared__ float red[256];
  __shared__ float ush[128];
  int t = threadIdx.x;
  if (t < 128) ush[t] = u[t];
  __syncthreads();
  float acc = 0.f;
  for (int k = 0; k < 128; k++) acc += Wk[(size_t)k * 256 + t] * ush[k];
  vsh[t] = acc;
  red[t] = acc * acc;
  __syncthreads();
  for (int s = 128; s > 0; s >>= 1) { if (t < s) red[t] += red[t + s]; __syncthreads(); }
  float nrm = sqrtf(red[0]) + 1e-12f;
  float vn = vsh[t] / nrm;
  __syncthreads();
  vsh[t] = vn;
  __syncthreads();
  float acc2 = 0.f;
  if (t < 128) {
    for (int c = 0; c < 256; c++) acc2 += Wk[(size_t)t * 256 + c] * vsh[c];
  }
  red[t] = (t < 128) ? acc2 * acc2 : 0.f;
  __syncthreads();
  for (int s = 128; s > 0; s >>= 1) { if (t < s) red[t] += red[t + s]; __syncthreads(); }
  if (t == 0) {
    float s2v = red[0];
    sig[0] = s2v / (sqrtf(s2v) + 1e-12f);
  }
}

// ---------------- K2b: Ww|Wk|Wv f32 -> bf16 wcat ---------------------------
__launch_bounds__(256)
__global__ void k_prep(const float* __restrict__ Ww, const float* __restrict__ Wk,
                       const float* __restrict__ Wv, unsigned short* __restrict__ wcat) {
  int i = (blockIdx.x * 256 + threadIdx.x) * 4;       // 98304 total
  const float* src = (i < 32768) ? (Ww + i) : (i < 65536) ? (Wk + i - 32768)
                                                          : (Wv + i - 65536);
  float4 w = *(const float4*)src;
  unsigned int lo = (unsigned int)f2bf(w.x) | ((unsigned int)f2bf(w.y) << 16);
  unsigned int hi = (unsigned int)f2bf(w.z) | ((unsigned int)f2bf(w.w) << 16);
  *(uint2*)(wcat + i) = make_uint2(lo, hi);
}

// ---------------- K3: fused projections via MFMA ---------------------------
// grid 256 = b(4) x nt(64, 64 n each). 4 waves: wid<2 -> q rows (Wk/sigma+bk,
// store qkT col-swizzled), wid>=2 -> v rows (Wv+bv, store vws 64-tile swizzled).
__launch_bounds__(256)
__global__ void k_qkv(const unsigned short* __restrict__ xfb,
                      const unsigned short* __restrict__ wcat,
                      const float* __restrict__ bk, const float* __restrict__ bv,
                      const float* __restrict__ sig,
                      unsigned short* __restrict__ qkT, unsigned short* __restrict__ vws) {
  __shared__ __align__(16) unsigned short Bl[64 * 64];   // [n][64k], kg-XOR swizzle
  int bid = blockIdx.x;
  int nt = bid & 63, b = bid >> 6;
  int n0 = nt * 64;
  int t = threadIdx.x, wid = t >> 6, lane = t & 63, g = lane >> 4, lr = lane & 15;
  int R0 = wid * 64;
  bool isq = (wid < 2);
  const unsigned short* wb = isq ? (wcat + 32768 + (size_t)R0 * 256)
                                 : (wcat + 65536 + (size_t)(R0 - 128) * 256);
  f32x4 acc[4][4];
#pragma unroll
  for (int i = 0; i < 4; i++)
#pragma unroll
    for (int j = 0; j < 4; j++) acc[i][j] = (f32x4){0.f, 0.f, 0.f, 0.f};

  short8 st[2];
#pragma unroll
  for (int i = 0; i < 2; i++) {
    int gid = i * 256 + t;
    st[i] = *(const short8*)(xfb + ((size_t)(b * 256 + (gid >> 3))) * 4096 +
                             n0 + (gid & 7) * 8);
  }

#pragma unroll 1
  for (int ks4 = 0; ks4 < 4; ks4++) {
    int k0 = ks4 * 64;
    __syncthreads();
#pragma unroll
    for (int i = 0; i < 2; i++) {
      int gid = i * 256 + t;
      int c = gid >> 3, nch = gid & 7;
#pragma unroll
      for (int j = 0; j < 8; j++) {
        int n = nch * 8 + j;
        Bl[n * 64 + (((c >> 3) ^ (n & 7)) << 3) + (c & 7)] = (unsigned short)st[i][j];
      }
    }
    if (ks4 < 3) {
#pragma unroll
      for (int i = 0; i < 2; i++) {
        int gid = i * 256 + t;
        st[i] = *(const short8*)(xfb + ((size_t)(b * 256 + k0 + 64 + (gid >> 3))) * 4096 +
                                 n0 + (gid & 7) * 8);
      }
    }
    __syncthreads();
#pragma unroll
    for (int ks2 = 0; ks2 < 2; ks2++) {
      short8 af[4], bf[4];
#pragma unroll
      for (int ot = 0; ot < 4; ot++)
        af[ot] = *(const short8*)(wb + (size_t)(ot * 16 + lr) * 256 + k0 + ks2 * 32 + g * 8);
#pragma unroll
      for (int nt2 = 0; nt2 < 4; nt2++) {
        int n = nt2 * 16 + lr;
        bf[nt2] = *(const short8*)(Bl + n * 64 + (((ks2 * 4 + g) ^ (n & 7)) << 3));
      }
#pragma unroll
      for (int ot = 0; ot < 4; ot++)
#pragma unroll
        for (int nt2 = 0; nt2 < 4; nt2++)
          acc[ot][nt2] = __builtin_amdgcn_mfma_f32_16x16x32_bf16(af[ot], bf[nt2],
                                                                 acc[ot][nt2], 0, 0, 0);
    }
  }

  if (isq) {
    float inv_s = 1.0f / sig[0];
#pragma unroll
    for (int ot = 0; ot < 4; ot++)
#pragma unroll
      for (int rr = 0; rr < 4; rr++) {
        int d = R0 + ot * 16 + g * 4 + rr;
        float bias = bk[d];
#pragma unroll
        for (int nt2 = 0; nt2 < 4; nt2++) {
          int n = n0 + nt2 * 16 + lr;
          float val = acc[ot][nt2][rr] * inv_s + bias;
          int ds = ((((d >> 3) ^ (n & 7)) & 15) << 3) | (d & 7);
          qkT[((size_t)b * 4096 + n) * 128 + ds] = f2bf(val);
        }
      }
  } else {
#pragma unroll
    for (int ot = 0; ot < 4; ot++)
#pragma unroll
      for (int rr = 0; rr < 4; rr++) {
        int d = R0 - 128 + ot * 16 + g * 4 + rr;
        float bias = bv[d];
#pragma unroll
        for (int nt2 = 0; nt2 < 4; nt2++) {
          int n = n0 + nt2 * 16 + lr;
          int c = n & 63;
          int cs = ((((c >> 3) ^ (d & 7)) & 7) << 3) | (c & 7);
          vws[((size_t)(b * 128 + d)) * 4096 + (n & ~63) + cs] =
              f2bf(acc[ot][nt2][rr] + bias);
        }
      }
  }
}

// ---------------- K4: flash attention, 8-wave blocks, LDS K+V --------------
// grid 512 = b(4) x qt(16, 256 q-rows) x sp(8, 512 kv). 8 waves, 32 q-rows each.
// K/V staged in LDS per 64-kv tile (reg-dbuf), no-max exp2 softmax, deferred l.
__launch_bounds__(512, 4)
__global__ void k_attn(const unsigned short* __restrict__ qkT,
                       const unsigned short* __restrict__ vws,
                       unsigned short* __restrict__ pc, float* __restrict__ lsum) {
  __shared__ __align__(16) char smem[16384 + 16384 + 8 * 4608];
  const float C1 = 0.12751744f;        // (1/sqrt(128)) * log2(e)
  int p = blockIdx.x;
  int bid = (p & 7) * 64 + (p >> 3);   // XCD swizzle (512 % 8 == 0)
  int sp = bid & 7, qt = (bid >> 3) & 15, b = bid >> 7;
  int kv0 = sp * 512;
  int t = threadIdx.x, wid = t >> 6, lane = t & 63, g = lane >> 4, lr = lane & 15;
  int qrb = qt * 256 + wid * 32;
  const unsigned short* qk_b = qkT + (size_t)b * 524288;
  const char* kgb = (const char*)qk_b;
  const char* vgb = (const char*)(vws + (size_t)b * 524288);
  char* KL = smem;
  char* VL = smem + 16384;
  unsigned short* PL = (unsigned short*)(smem + 32768 + wid * 4608);  // [32][72]

  // Q fragments (unswizzle stored layout)
  short8 qf[2][4];
#pragma unroll
  for (int rt = 0; rt < 2; rt++)
#pragma unroll
    for (int kk = 0; kk < 4; kk++) {
      int row = qrb + rt * 16 + lr;
      qf[rt][kk] = *(const short8*)(qk_b + (size_t)row * 128 +
                                    ((((kk * 4 + g) ^ (lr & 7)) & 15) << 3));
    }

  f32x4 cacc[2][8];
#pragma unroll
  for (int rt = 0; rt < 2; rt++)
#pragma unroll
    for (int vt = 0; vt < 8; vt++) cacc[rt][vt] = (f32x4){0.f, 0.f, 0.f, 0.f};
  float l0[4] = {0.f, 0.f, 0.f, 0.f}, l1[4] = {0.f, 0.f, 0.f, 0.f};

  // staging assignment (512 threads): K row = gid>>4 (256B rows), V row = gid>>3
  short8 kst[2], vst[2];
#pragma unroll
  for (int i = 0; i < 2; i++) {
    int gid = i * 512 + t;
    kst[i] = *(const short8*)(kgb + (size_t)(kv0 + (gid >> 4)) * 256 + (gid & 15) * 16);
    vst[i] = *(const short8*)(vgb + (size_t)(gid >> 3) * 8192 + kv0 * 2 + (gid & 7) * 16);
  }

#pragma unroll 1
  for (int it = 0; it < 8; ++it) {
    int mbase = kv0 + it * 64;
    __syncthreads();
#pragma unroll
    for (int i = 0; i < 2; i++) {
      int gid = i * 512 + t;
      *(short8*)(KL + (gid >> 4) * 256 + (gid & 15) * 16) = kst[i];
      *(short8*)(VL + (gid >> 3) * 128 + (gid & 7) * 16) = vst[i];
    }
    if (it < 7) {
      int mb = mbase + 64;
#pragma unroll
      for (int i = 0; i < 2; i++) {
        int gid = i * 512 + t;
        kst[i] = *(const short8*)(kgb + (size_t)(mb + (gid >> 4)) * 256 + (gid & 15) * 16);
        vst[i] = *(const short8*)(vgb + (size_t)(gid >> 3) * 8192 + mb * 2 + (gid & 7) * 16);
      }
    }
    __syncthreads();

    // ---- QK^T + no-max softmax, per 16-kv column tile ----
#pragma unroll
    for (int ct = 0; ct < 4; ct++) {
      short8 kf[4];
#pragma unroll
      for (int kk = 0; kk < 4; kk++)
        kf[kk] = *(const short8*)(KL + (ct * 16 + lr) * 256 +
                                  ((((kk * 4 + g) ^ (lr & 7)) & 15) << 4));
      f32x4 a0 = {0.f, 0.f, 0.f, 0.f}, a1 = a0;
#pragma unroll
      for (int kk = 0; kk < 4; kk++) {
        a0 = __builtin_amdgcn_mfma_f32_16x16x32_bf16(qf[0][kk], kf[kk], a0, 0, 0, 0);
        a1 = __builtin_amdgcn_mfma_f32_16x16x32_bf16(qf[1][kk], kf[kk], a1, 0, 0, 0);
      }
#pragma unroll
      for (int r = 0; r < 4; r++) {
        float p0 = __builtin_amdgcn_exp2f(a0[r] * C1);
        float p1 = __builtin_amdgcn_exp2f(a1[r] * C1);
        l0[r] += p0;
        l1[r] += p1;
        PL[(g * 4 + r) * 72 + ct * 16 + lr] =
            (unsigned short)((__float_as_uint(p0) + 0x8000u) >> 16);
        PL[(16 + g * 4 + r) * 72 + ct * 16 + lr] =
            (unsigned short)((__float_as_uint(p1) + 0x8000u) >> 16);
      }
    }

    // ---- PV ----
    __builtin_amdgcn_s_setprio(1);
#pragma unroll
    for (int ks = 0; ks < 2; ks++) {
      short8 pa0 = *(const short8*)(PL + lr * 72 + ks * 32 + g * 8);
      short8 pa1 = *(const short8*)(PL + (16 + lr) * 72 + ks * 32 + g * 8);
#pragma unroll
      for (int vt = 0; vt < 8; vt++) {
        short8 vb = *(const short8*)(VL + (vt * 16 + lr) * 128 +
                                     ((((ks * 4 + g) ^ (lr & 7)) & 7) << 4));
        cacc[0][vt] = __builtin_amdgcn_mfma_f32_16x16x32_bf16(pa0, vb, cacc[0][vt], 0, 0, 0);
        cacc[1][vt] = __builtin_amdgcn_mfma_f32_16x16x32_bf16(pa1, vb, cacc[1][vt], 0, 0, 0);
      }
    }
    __builtin_amdgcn_s_setprio(0);
  }

  // ---- deferred l reduce (over 16-lane group) ----
#pragma unroll
  for (int r = 0; r < 4; r++) {
    float v = l0[r];
    v += __shfl_xor(v, 1); v += __shfl_xor(v, 2);
    v += __shfl_xor(v, 4); v += __shfl_xor(v, 8);
    l0[r] = v;
    float w = l1[r];
    w += __shfl_xor(w, 1); w += __shfl_xor(w, 2);
    w += __shfl_xor(w, 4); w += __shfl_xor(w, 8);
    l1[r] = w;
  }

  // ---- epilogue: bf16 partials + l ----
#pragma unroll
  for (int rt = 0; rt < 2; rt++)
#pragma unroll
    for (int vt = 0; vt < 8; vt++)
#pragma unroll
      for (int r = 0; r < 4; r++) {
        int n = qrb + rt * 16 + g * 4 + r;
        size_t gn = (size_t)b * 4096 + n;
        float v = rt ? cacc[1][vt][r] : cacc[0][vt][r];
        pc[((size_t)sp * 16384 + gn) * 128 + vt * 16 + lr] = f2bf(v);
      }
  if (lr == 0) {
#pragma unroll
    for (int rt = 0; rt < 2; rt++)
#pragma unroll
      for (int r = 0; r < 4; r++) {
        int n = qrb + rt * 16 + g * 4 + r;
        size_t gn = (size_t)b * 4096 + n;
        lsum[sp * 16384 + gn] = rt ? l1[r] : l0[r];
      }
  }
}

// ---------------- K5: fused merge + output projection (MFMA) ---------------
__launch_bounds__(256)
__global__ void k_mergeout(const unsigned short* __restrict__ pc,
                           const float* __restrict__ lsum,
                           const unsigned short* __restrict__ wwb,
                           const float* __restrict__ bw,
                           float* __restrict__ out) {
  __shared__ float inv_l[64];
  __shared__ __align__(16) unsigned short Bl[64 * 128];
  int bid = blockIdx.x;
  int nt = bid & 63, b = bid >> 6;
  int n0 = nt * 64;
  size_t gnb = (size_t)b * 4096 + n0;
  int t = threadIdx.x;

  if (t < 64) {
    float L = 0.f;
#pragma unroll
    for (int sp = 0; sp < 8; sp++) L += lsum[sp * 16384 + gnb + t];
    inv_l[t] = 1.f / L;
  }
  __syncthreads();

  {  // merge 32 values per thread: n = t&63, v = (t>>6)*32 ..
    int n = t & 63, vs = t >> 6;
    float o[32] = {};
#pragma unroll
    for (int sp = 0; sp < 8; sp++) {
      const unsigned short* src = pc + ((size_t)sp * 16384 + gnb + n) * 128 + vs * 32;
#pragma unroll
      for (int c = 0; c < 4; c++) {
        short8 pv = *(const short8*)(src + c * 8);
#pragma unroll
        for (int j = 0; j < 8; j++) o[c * 8 + j] += bf2f((unsigned short)pv[j]);
      }
    }
    float inv = inv_l[n];
    unsigned int* B32 = (unsigned int*)Bl;
#pragma unroll
    for (int jj = 0; jj < 16; jj++) {
      int v = vs * 32 + jj * 2;
      int kg = v >> 3;
      int kgp = (kg & 8) | ((kg ^ n) & 7);
      unsigned int pk = (unsigned int)f2bf(o[jj * 2] * inv) |
                        ((unsigned int)f2bf(o[jj * 2 + 1] * inv) << 16);
      B32[n * 64 + kgp * 4 + ((v & 7) >> 1)] = pk;
    }
  }
  __syncthreads();

  int wid = t >> 6, lane = t & 63, g = lane >> 4, lr = lane & 15;
  int o0 = wid * 64;
  short8 af[4][4];
#pragma unroll
  for (int ot = 0; ot < 4; ot++) {
    int o = o0 + ot * 16 + lr;
#pragma unroll
    for (int ks = 0; ks < 4; ks++)
      af[ot][ks] = *(const short8*)(wwb + (size_t)o * 128 + ks * 32 + g * 8);
  }
  f32x4 acc[4][4];
#pragma unroll
  for (int i = 0; i < 4; i++)
#pragma unroll
    for (int j = 0; j < 4; j++) acc[i][j] = (f32x4){0.f, 0.f, 0.f, 0.f};
#pragma unroll
  for (int nt2 = 0; nt2 < 4; nt2++) {
    short8 bfr[4];
#pragma unroll
    for (int ks = 0; ks < 4; ks++) {
      int kg = ks * 4 + g;
      int kgp = (kg & 8) | ((kg ^ lr) & 7);
      bfr[ks] = *(const short8*)(Bl + (nt2 * 16 + lr) * 128 + kgp * 8);
    }
#pragma unroll
    for (int ot = 0; ot < 4; ot++)
#pragma unroll
      for (int ks = 0; ks < 4; ks++)
        acc[ot][nt2] = __builtin_amdgcn_mfma_f32_16x16x32_bf16(af[ot][ks], bfr[ks],
                                                               acc[ot][nt2], 0, 0, 0);
  }
#pragma unroll
  for (int ot = 0; ot < 4; ot++)
#pragma unroll
    for (int r = 0; r < 4; r++) {
      int o = o0 + ot * 16 + g * 4 + r;
      float bias = bw[o];
#pragma unroll
      for (int nt2 = 0; nt2 < 4; nt2++)
        out[((size_t)(b * 256 + o)) * 4096 + n0 + nt2 * 16 + lr] = acc[ot][nt2][r] + bias;
    }
}

extern "C" void kernel_launch(void* const* d_in, const int* in_sizes, int n_in,
                              void* d_out, int out_size, void* d_ws, size_t ws_size,
                              hipStream_t stream) {
  const float* x  = (const float*)d_in[0];
  const float* Wk = (const float*)d_in[1];
  const float* bk = (const float*)d_in[2];
  const float* Wv = (const float*)d_in[3];
  const float* bv = (const float*)d_in[4];
  const float* Ww = (const float*)d_in[5];
  const float* bw = (const float*)d_in[6];
  const float* u  = (const float*)d_in[7];

  char* ws = (char*)d_ws;
  float* sig            = (float*)(ws + OFF_SIGMA);
  float* lsum           = (float*)(ws + OFF_ML);
  unsigned short* qkT   = (unsigned short*)(ws + OFF_QKT);
  unsigned short* vbuf  = (unsigned short*)(ws + OFF_V);
  unsigned short* wcat  = (unsigned short*)(ws + OFF_WCAT);
  unsigned short* xfb   = (unsigned short*)(ws + OFF_XFB);
  unsigned short* pc    = (unsigned short*)(ws + OFF_PC);
  float* out            = (float*)d_out;

  k_maxpool<<<8192, 256, 0, stream>>>(x, xfb);
  k_sigma<<<1, 256, 0, stream>>>(Wk, u, sig);
  k_prep<<<96, 256, 0, stream>>>(Ww, Wk, Wv, wcat);
  k_qkv<<<256, 256, 0, stream>>>(xfb, wcat, bk, bv, sig, qkT, vbuf);
  k_attn<<<512, 512, 0, stream>>>(qkT, vbuf, pc, lsum);
  k_mergeout<<<256, 256, 0, stream>>>(pc, lsum, wcat, bw, out);
}

// Round 7
// 107.933 us; speedup vs baseline: 2.6434x; 2.3263x over previous
//
#include <hip/hip_runtime.h>

typedef __attribute__((ext_vector_type(8))) short short8;
typedef __attribute__((ext_vector_type(4))) float f32x4;

// B=4, C=256, pooled N=4096, kc=vc=128, oc=256
static constexpr size_t OFF_SIGMA = 0;
static constexpr size_t OFF_ML    = 256;                        // float[8][16384] row-sums
static constexpr size_t OFF_QKT   = 1048576;                    // bf16 [4][4096][128] (col-swizzled)
static constexpr size_t OFF_V     = OFF_QKT + 4194304;          // bf16 [4][128][4096] (64-tile swizzled)
static constexpr size_t OFF_WCAT  = OFF_V + 4194304;            // bf16 Ww[256][128] | Wk[128][256] | Wv[128][256]
static constexpr size_t OFF_XFB   = OFF_WCAT + 196608;          // bf16 [4*256][4096]
static constexpr size_t OFF_PC    = OFF_XFB;                    // bf16 [8][16384][128] (aliases xfb; xfb dead by attn)

__device__ inline unsigned short f2bf(float f) {
  unsigned int u = __float_as_uint(f);
  unsigned int r = u + 0x7fffu + ((u >> 16) & 1u);
  return (unsigned short)(r >> 16);
}
__device__ inline float bf2f(unsigned short s) {
  return __uint_as_float(((unsigned int)s) << 16);
}

// ---------------- K1: maxpool3d(2) -> xfb bf16 [4,256,4096] ----------------
__launch_bounds__(256)
__global__ void k_maxpool(const float* __restrict__ x, unsigned short* __restrict__ xfb) {
  int idx = blockIdx.x * 256 + threadIdx.x;      // 2 outputs per thread
  int n2 = idx & 2047;
  int bc = idx >> 11;
  int d2p = n2 & 7, d1 = (n2 >> 3) & 15, d0 = n2 >> 7;
  const float* p = x + (size_t)bc * 32768 + (size_t)d0 * 2048 + d1 * 64 + d2p * 4;
  float4 a = *(const float4*)(p);
  float4 b = *(const float4*)(p + 32);
  float4 c = *(const float4*)(p + 1024);
  float4 e = *(const float4*)(p + 1056);
  float o0 = fmaxf(fmaxf(fmaxf(a.x, a.y), fmaxf(b.x, b.y)),
                   fmaxf(fmaxf(c.x, c.y), fmaxf(e.x, e.y)));
  float o1 = fmaxf(fmaxf(fmaxf(a.z, a.w), fmaxf(b.z, b.w)),
                   fmaxf(fmaxf(c.z, c.w), fmaxf(e.z, e.w)));
  unsigned int pk = (unsigned int)f2bf(o0) | ((unsigned int)f2bf(o1) << 16);
  *(unsigned int*)(xfb + (size_t)bc * 4096 + n2 * 2) = pk;
}

// ---------------- K2: spectral-norm sigma ----------------------------------
__global__ void k_sigma(const float* __restrict__ Wk, const float* __restrict__ u,
                        float* __restrict__ sig) {
  __shared__ float vsh[256];
  __shared__ float red[256];
  __shared__ float ush[128];
  int t = threadIdx.x;
  if (t < 128) ush[t] = u[t];
  __syncthreads();
  float acc = 0.f;
  for (int k = 0; k < 128; k++) acc += Wk[(size_t)k * 256 + t] * ush[k];
  vsh[t] = acc;
  red[t] = acc * acc;
  __syncthreads();
  for (int s = 128; s > 0; s >>= 1) { if (t < s) red[t] += red[t + s]; __syncthreads(); }
  float nrm = sqrtf(red[0]) + 1e-12f;
  float vn = vsh[t] / nrm;
  __syncthreads();
  vsh[t] = vn;
  __syncthreads();
  float acc2 = 0.f;
  if (t < 128) {
    for (int c = 0; c < 256; c++) acc2 += Wk[(size_t)t * 256 + c] * vsh[c];
  }
  red[t] = (t < 128) ? acc2 * acc2 : 0.f;
  __syncthreads();
  for (int s = 128; s > 0; s >>= 1) { if (t < s) red[t] += red[t + s]; __syncthreads(); }
  if (t == 0) {
    float s2v = red[0];
    sig[0] = s2v / (sqrtf(s2v) + 1e-12f);
  }
}

// ---------------- K2b: Ww|Wk|Wv f32 -> bf16 wcat ---------------------------
__launch_bounds__(256)
__global__ void k_prep(const float* __restrict__ Ww, const float* __restrict__ Wk,
                       const float* __restrict__ Wv, unsigned short* __restrict__ wcat) {
  int i = (blockIdx.x * 256 + threadIdx.x) * 4;       // 98304 total
  const float* src = (i < 32768) ? (Ww + i) : (i < 65536) ? (Wk + i - 32768)
                                                          : (Wv + i - 65536);
  float4 w = *(const float4*)src;
  unsigned int lo = (unsigned int)f2bf(w.x) | ((unsigned int)f2bf(w.y) << 16);
  unsigned int hi = (unsigned int)f2bf(w.z) | ((unsigned int)f2bf(w.w) << 16);
  *(uint2*)(wcat + i) = make_uint2(lo, hi);
}

// ---------------- K3: fused projections via MFMA ---------------------------
__launch_bounds__(256)
__global__ void k_qkv(const unsigned short* __restrict__ xfb,
                      const unsigned short* __restrict__ wcat,
                      const float* __restrict__ bk, const float* __restrict__ bv,
                      const float* __restrict__ sig,
                      unsigned short* __restrict__ qkT, unsigned short* __restrict__ vws) {
  __shared__ __align__(16) unsigned short Bl[64 * 64];   // [n][64k], kg-XOR swizzle
  int bid = blockIdx.x;
  int nt = bid & 63, b = bid >> 6;
  int n0 = nt * 64;
  int t = threadIdx.x, wid = t >> 6, lane = t & 63, g = lane >> 4, lr = lane & 15;
  int R0 = wid * 64;
  bool isq = (wid < 2);
  const unsigned short* wb = isq ? (wcat + 32768 + (size_t)R0 * 256)
                                 : (wcat + 65536 + (size_t)(R0 - 128) * 256);
  f32x4 acc[4][4];
#pragma unroll
  for (int i = 0; i < 4; i++)
#pragma unroll
    for (int j = 0; j < 4; j++) acc[i][j] = (f32x4){0.f, 0.f, 0.f, 0.f};

  short8 st[2];
#pragma unroll
  for (int i = 0; i < 2; i++) {
    int gid = i * 256 + t;
    st[i] = *(const short8*)(xfb + ((size_t)(b * 256 + (gid >> 3))) * 4096 +
                             n0 + (gid & 7) * 8);
  }

#pragma unroll 1
  for (int ks4 = 0; ks4 < 4; ks4++) {
    int k0 = ks4 * 64;
    __syncthreads();
#pragma unroll
    for (int i = 0; i < 2; i++) {
      int gid = i * 256 + t;
      int c = gid >> 3, nch = gid & 7;
#pragma unroll
      for (int j = 0; j < 8; j++) {
        int n = nch * 8 + j;
        Bl[n * 64 + (((c >> 3) ^ (n & 7)) << 3) + (c & 7)] = (unsigned short)st[i][j];
      }
    }
    if (ks4 < 3) {
#pragma unroll
      for (int i = 0; i < 2; i++) {
        int gid = i * 256 + t;
        st[i] = *(const short8*)(xfb + ((size_t)(b * 256 + k0 + 64 + (gid >> 3))) * 4096 +
                                 n0 + (gid & 7) * 8);
      }
    }
    __syncthreads();
#pragma unroll
    for (int ks2 = 0; ks2 < 2; ks2++) {
      short8 af[4], bf[4];
#pragma unroll
      for (int ot = 0; ot < 4; ot++)
        af[ot] = *(const short8*)(wb + (size_t)(ot * 16 + lr) * 256 + k0 + ks2 * 32 + g * 8);
#pragma unroll
      for (int nt2 = 0; nt2 < 4; nt2++) {
        int n = nt2 * 16 + lr;
        bf[nt2] = *(const short8*)(Bl + n * 64 + (((ks2 * 4 + g) ^ (n & 7)) << 3));
      }
#pragma unroll
      for (int ot = 0; ot < 4; ot++)
#pragma unroll
        for (int nt2 = 0; nt2 < 4; nt2++)
          acc[ot][nt2] = __builtin_amdgcn_mfma_f32_16x16x32_bf16(af[ot], bf[nt2],
                                                                 acc[ot][nt2], 0, 0, 0);
    }
  }

  if (isq) {
    float inv_s = 1.0f / sig[0];
#pragma unroll
    for (int ot = 0; ot < 4; ot++)
#pragma unroll
      for (int rr = 0; rr < 4; rr++) {
        int d = R0 + ot * 16 + g * 4 + rr;
        float bias = bk[d];
#pragma unroll
        for (int nt2 = 0; nt2 < 4; nt2++) {
          int n = n0 + nt2 * 16 + lr;
          float val = acc[ot][nt2][rr] * inv_s + bias;
          int ds = ((((d >> 3) ^ (n & 7)) & 15) << 3) | (d & 7);
          qkT[((size_t)b * 4096 + n) * 128 + ds] = f2bf(val);
        }
      }
  } else {
#pragma unroll
    for (int ot = 0; ot < 4; ot++)
#pragma unroll
      for (int rr = 0; rr < 4; rr++) {
        int d = R0 - 128 + ot * 16 + g * 4 + rr;
        float bias = bv[d];
#pragma unroll
        for (int nt2 = 0; nt2 < 4; nt2++) {
          int n = n0 + nt2 * 16 + lr;
          int c = n & 63;
          int cs = ((((c >> 3) ^ (d & 7)) & 7) << 3) | (c & 7);
          vws[((size_t)(b * 128 + d)) * 4096 + (n & ~63) + cs] =
              f2bf(acc[ot][nt2][rr] + bias);
        }
      }
  }
}

// ---------------- K4: flash attention (R4 shell + softmax diet) ------------
// grid 1024 = b(4) x qt(32, 128 q-rows) x sp(8, 512 kv). 4 waves, 32 q-rows
// each. K/V staged in LDS per 64-kv tile (reg dbuf). No-max exp2 softmax,
// per-lane deferred l. Coalesced pc epilogue via LDS transpose.
__launch_bounds__(256, 2)
__global__ void k_attn(const unsigned short* __restrict__ qkT,
                       const unsigned short* __restrict__ vws,
                       unsigned short* __restrict__ pc, float* __restrict__ lsum) {
  __shared__ __align__(16) char smem[16384 + 16384 + 4 * 4608];  // K | V | P x4
  const float C1 = 0.12751744f;        // (1/sqrt(128)) * log2(e)
  int p = blockIdx.x;
  int bid = (p & 7) * 128 + (p >> 3);  // XCD swizzle (1024 % 8 == 0)
  int sp = bid & 7, qt = (bid >> 3) & 31, b = bid >> 8;
  int kv0 = sp * 512;
  int t = threadIdx.x, wid = t >> 6, lane = t & 63, g = lane >> 4, lr = lane & 15;
  int qrb = qt * 128 + wid * 32;
  const unsigned short* qk_b = qkT + (size_t)b * 524288;
  const char* kgb = (const char*)qk_b;
  const char* vgb = (const char*)(vws + (size_t)b * 524288);
  char* KL = smem;
  char* VL = smem + 16384;
  unsigned short* PL = (unsigned short*)(smem + 32768 + wid * 4608);  // [32][72]

  // Q fragments (unswizzle stored layout)
  short8 qf[2][4];
#pragma unroll
  for (int rt = 0; rt < 2; rt++)
#pragma unroll
    for (int kk = 0; kk < 4; kk++) {
      int row = qrb + rt * 16 + lr;
      qf[rt][kk] = *(const short8*)(qk_b + (size_t)row * 128 +
                                    ((((kk * 4 + g) ^ (lr & 7)) & 15) << 3));
    }

  f32x4 cacc[2][8];
#pragma unroll
  for (int rt = 0; rt < 2; rt++)
#pragma unroll
    for (int vt = 0; vt < 8; vt++) cacc[rt][vt] = (f32x4){0.f, 0.f, 0.f, 0.f};
  float l0[4] = {0.f, 0.f, 0.f, 0.f}, l1[4] = {0.f, 0.f, 0.f, 0.f};

  int drow = t >> 3;            // V stage row within 32-row chunk
  int cb   = (t & 7) * 16;      // byte col within 128B

  short8 kst[4], vst[4];
  {
    const char* kg = kgb + (size_t)kv0 * 256;
#pragma unroll
    for (int i = 0; i < 4; i++) kst[i] = *(const short8*)(kg + i * 4096 + t * 16);
#pragma unroll
    for (int i = 0; i < 4; i++)
      vst[i] = *(const short8*)(vgb + (size_t)(i * 32 + drow) * 8192 + kv0 * 2 + cb);
  }

#pragma unroll 1
  for (int it = 0; it < 8; ++it) {
    int mbase = kv0 + it * 64;
    __syncthreads();
#pragma unroll
    for (int i = 0; i < 4; i++) *(short8*)(KL + i * 4096 + t * 16) = kst[i];
#pragma unroll
    for (int i = 0; i < 4; i++) *(short8*)(VL + i * 4096 + t * 16) = vst[i];
    if (it < 7) {
      int mb = mbase + 64;
      const char* kg = kgb + (size_t)mb * 256;
#pragma unroll
      for (int i = 0; i < 4; i++) kst[i] = *(const short8*)(kg + i * 4096 + t * 16);
#pragma unroll
      for (int i = 0; i < 4; i++)
        vst[i] = *(const short8*)(vgb + (size_t)(i * 32 + drow) * 8192 + mb * 2 + cb);
    }
    __syncthreads();

    // ---- QK^T + no-max exp2 softmax, per 16-kv column tile ----
#pragma unroll
    for (int ct = 0; ct < 4; ct++) {
      short8 kf[4];
#pragma unroll
      for (int kk = 0; kk < 4; kk++)
        kf[kk] = *(const short8*)(KL + (ct * 16 + lr) * 256 +
                                  ((((kk * 4 + g) ^ (lr & 7)) & 15) << 4));
      f32x4 a0 = {0.f, 0.f, 0.f, 0.f}, a1 = a0;
      __builtin_amdgcn_s_setprio(1);
#pragma unroll
      for (int kk = 0; kk < 4; kk++) {
        a0 = __builtin_amdgcn_mfma_f32_16x16x32_bf16(qf[0][kk], kf[kk], a0, 0, 0, 0);
        a1 = __builtin_amdgcn_mfma_f32_16x16x32_bf16(qf[1][kk], kf[kk], a1, 0, 0, 0);
      }
      __builtin_amdgcn_s_setprio(0);
#pragma unroll
      for (int r = 0; r < 4; r++) {
        float p0 = __builtin_amdgcn_exp2f(a0[r] * C1);
        float p1 = __builtin_amdgcn_exp2f(a1[r] * C1);
        l0[r] += p0;
        l1[r] += p1;
        PL[(g * 4 + r) * 72 + ct * 16 + lr] =
            (unsigned short)((__float_as_uint(p0) + 0x8000u) >> 16);
        PL[(16 + g * 4 + r) * 72 + ct * 16 + lr] =
            (unsigned short)((__float_as_uint(p1) + 0x8000u) >> 16);
      }
    }

    // ---- PV ----
    __builtin_amdgcn_s_setprio(1);
#pragma unroll
    for (int ks = 0; ks < 2; ks++) {
      short8 pa0 = *(const short8*)(PL + lr * 72 + ks * 32 + g * 8);
      short8 pa1 = *(const short8*)(PL + (16 + lr) * 72 + ks * 32 + g * 8);
#pragma unroll
      for (int vt = 0; vt < 8; vt++) {
        short8 vb = *(const short8*)(VL + (vt * 16 + lr) * 128 +
                                     ((((ks * 4 + g) ^ (lr & 7)) & 7) << 4));
        cacc[0][vt] = __builtin_amdgcn_mfma_f32_16x16x32_bf16(pa0, vb, cacc[0][vt], 0, 0, 0);
        cacc[1][vt] = __builtin_amdgcn_mfma_f32_16x16x32_bf16(pa1, vb, cacc[1][vt], 0, 0, 0);
      }
    }
    __builtin_amdgcn_s_setprio(0);
  }

  // ---- deferred l reduce (over 16-lane group) ----
#pragma unroll
  for (int r = 0; r < 4; r++) {
    float v = l0[r];
    v += __shfl_xor(v, 1); v += __shfl_xor(v, 2);
    v += __shfl_xor(v, 4); v += __shfl_xor(v, 8);
    l0[r] = v;
    float w = l1[r];
    w += __shfl_xor(w, 1); w += __shfl_xor(w, 2);
    w += __shfl_xor(w, 4); w += __shfl_xor(w, 8);
    l1[r] = w;
  }

  // ---- epilogue: LDS transpose (stride 136) + coalesced 16B stores ----
  int rowrd = lane >> 4;            // 0..3
  int colrd = (lane & 15) * 8;      // 0..120
#pragma unroll
  for (int rt = 0; rt < 2; rt++) {
#pragma unroll
    for (int vt = 0; vt < 8; vt++)
#pragma unroll
      for (int r = 0; r < 4; r++)
        PL[(g * 4 + r) * 136 + vt * 16 + lr] =
            f2bf(rt ? cacc[1][vt][r] : cacc[0][vt][r]);
#pragma unroll
    for (int rnd = 0; rnd < 4; rnd++) {
      int row = rnd * 4 + rowrd;
      short8 v = *(const short8*)(PL + row * 136 + colrd);
      int n = qrb + rt * 16 + row;
      *(short8*)(pc + ((size_t)sp * 16384 + (size_t)b * 4096 + n) * 128 + colrd) = v;
    }
  }
  if (lr == 0) {
#pragma unroll
    for (int rt = 0; rt < 2; rt++)
#pragma unroll
      for (int r = 0; r < 4; r++) {
        int n = qrb + rt * 16 + g * 4 + r;
        lsum[sp * 16384 + (size_t)b * 4096 + n] = rt ? l1[r] : l0[r];
      }
  }
}

// ---------------- K5: fused merge + output projection (MFMA) ---------------
__launch_bounds__(256)
__global__ void k_mergeout(const unsigned short* __restrict__ pc,
                           const float* __restrict__ lsum,
                           const unsigned short* __restrict__ wwb,
                           const float* __restrict__ bw,
                           float* __restrict__ out) {
  __shared__ float inv_l[64];
  __shared__ __align__(16) unsigned short Bl[64 * 128];
  int bid = blockIdx.x;
  int nt = bid & 63, b = bid >> 6;
  int n0 = nt * 64;
  size_t gnb = (size_t)b * 4096 + n0;
  int t = threadIdx.x;

  if (t < 64) {
    float L = 0.f;
#pragma unroll
    for (int sp = 0; sp < 8; sp++) L += lsum[sp * 16384 + gnb + t];
    inv_l[t] = 1.f / L;
  }
  __syncthreads();

  {  // merge 32 values per thread: n = t&63, v = (t>>6)*32 ..
    int n = t & 63, vs = t >> 6;
    float o[32] = {};
#pragma unroll
    for (int sp = 0; sp < 8; sp++) {
      const unsigned short* src = pc + ((size_t)sp * 16384 + gnb + n) * 128 + vs * 32;
#pragma unroll
      for (int c = 0; c < 4; c++) {
        short8 pv = *(const short8*)(src + c * 8);
#pragma unroll
        for (int j = 0; j < 8; j++) o[c * 8 + j] += bf2f((unsigned short)pv[j]);
      }
    }
    float inv = inv_l[n];
    unsigned int* B32 = (unsigned int*)Bl;
#pragma unroll
    for (int jj = 0; jj < 16; jj++) {
      int v = vs * 32 + jj * 2;
      int kg = v >> 3;
      int kgp = (kg & 8) | ((kg ^ n) & 7);
      unsigned int pk = (unsigned int)f2bf(o[jj * 2] * inv) |
                        ((unsigned int)f2bf(o[jj * 2 + 1] * inv) << 16);
      B32[n * 64 + kgp * 4 + ((v & 7) >> 1)] = pk;
    }
  }
  __syncthreads();

  int wid = t >> 6, lane = t & 63, g = lane >> 4, lr = lane & 15;
  int o0 = wid * 64;
  short8 af[4][4];
#pragma unroll
  for (int ot = 0; ot < 4; ot++) {
    int o = o0 + ot * 16 + lr;
#pragma unroll
    for (int ks = 0; ks < 4; ks++)
      af[ot][ks] = *(const short8*)(wwb + (size_t)o * 128 + ks * 32 + g * 8);
  }
  f32x4 acc[4][4];
#pragma unroll
  for (int i = 0; i < 4; i++)
#pragma unroll
    for (int j = 0; j < 4; j++) acc[i][j] = (f32x4){0.f, 0.f, 0.f, 0.f};
#pragma unroll
  for (int nt2 = 0; nt2 < 4; nt2++) {
    short8 bfr[4];
#pragma unroll
    for (int ks = 0; ks < 4; ks++) {
      int kg = ks * 4 + g;
      int kgp = (kg & 8) | ((kg ^ lr) & 7);
      bfr[ks] = *(const short8*)(Bl + (nt2 * 16 + lr) * 128 + kgp * 8);
    }
#pragma unroll
    for (int ot = 0; ot < 4; ot++)
#pragma unroll
      for (int ks = 0; ks < 4; ks++)
        acc[ot][nt2] = __builtin_amdgcn_mfma_f32_16x16x32_bf16(af[ot][ks], bfr[ks],
                                                               acc[ot][nt2], 0, 0, 0);
  }
#pragma unroll
  for (int ot = 0; ot < 4; ot++)
#pragma unroll
    for (int r = 0; r < 4; r++) {
      int o = o0 + ot * 16 + g * 4 + r;
      float bias = bw[o];
#pragma unroll
      for (int nt2 = 0; nt2 < 4; nt2++)
        out[((size_t)(b * 256 + o)) * 4096 + n0 + nt2 * 16 + lr] = acc[ot][nt2][r] + bias;
    }
}

extern "C" void kernel_launch(void* const* d_in, const int* in_sizes, int n_in,
                              void* d_out, int out_size, void* d_ws, size_t ws_size,
                              hipStream_t stream) {
  const float* x  = (const float*)d_in[0];
  const float* Wk = (const float*)d_in[1];
  const float* bk = (const float*)d_in[2];
  const float* Wv = (const float*)d_in[3];
  const float* bv = (const float*)d_in[4];
  const float* Ww = (const float*)d_in[5];
  const float* bw = (const float*)d_in[6];
  const float* u  = (const float*)d_in[7];

  char* ws = (char*)d_ws;
  float* sig            = (float*)(ws + OFF_SIGMA);
  float* lsum           = (float*)(ws + OFF_ML);
  unsigned short* qkT   = (unsigned short*)(ws + OFF_QKT);
  unsigned short* vbuf  = (unsigned short*)(ws + OFF_V);
  unsigned short* wcat  = (unsigned short*)(ws + OFF_WCAT);
  unsigned short* xfb   = (unsigned short*)(ws + OFF_XFB);
  unsigned short* pc    = (unsigned short*)(ws + OFF_PC);
  float* out            = (float*)d_out;

  k_maxpool<<<8192, 256, 0, stream>>>(x, xfb);
  k_sigma<<<1, 256, 0, stream>>>(Wk, u, sig);
  k_prep<<<96, 256, 0, stream>>>(Ww, Wk, Wv, wcat);
  k_qkv<<<256, 256, 0, stream>>>(xfb, wcat, bk, bv, sig, qkT, vbuf);
  k_attn<<<1024, 256, 0, stream>>>(qkT, vbuf, pc, lsum);
  k_mergeout<<<256, 256, 0, stream>>>(pc, lsum, wcat, bw, out);
}